// Round 10
// baseline (210.847 us; speedup 1.0000x reference)
//
#include <hip/hip_runtime.h>
#include <hip/hip_cooperative_groups.h>
#include <math.h>

namespace cg = cooperative_groups;

// Problem constants (fixed by setup_inputs): B=8, N=2048, C=128, TOP_K=512
// Algebraic structure (verified passing since R1):
//  - adj = softmax(relu(GL GL^T)) + I > 0 everywhere  => att == e, GL unused.
//  - e[b,i,j] = leaky_relu(p_i + q_j) monotone in p_i => keep iff
//    (p_i, -i) >= 512th largest; unselected rows => relu(mean_j h[b,j,:]).
//  - exp(leaky_relu(p+q)) separates at q >= -p; sorted-q order =>
//    suffix/prefix sums per row (boundary lo_i). p=x@(W@a1), q=x@(W@a2).
//
// Journal: R11 111.2 -> R13 106.3 -> R16 104.8 BEST -> R17/R18 linearity
// detour (k_out latency-bound, 45.2us measured) -> R20 FAILED absmax=0.2695
// == plausible max|ref| with out=0 => cooperative launch REJECTED silently
// (grid 264 > 256 CUs likely tripped 1-block/CU co-residency validation;
// return code was unchecked). Phase math verified identical to R16.
// TIMELINE MODEL (fits R14/R16/R18): fill ~42us + ~10us PER LAUNCH + kernels.
// R21: (a) grid = exactly 256: scalar scans fold into P2 blocks 0..7
//      (block-uniform branch between gather and chunk-scan compute);
//      (b) phase arg + CHECKED launch: coop fails -> 4 normal per-phase
//      launches of the same kernel (== R16 behavior, worst case ~110us).

#define B_ 8
#define N_ 2048
#define C_ 128
#define TOPK_ 512
#define NCH_ 32      // chunks per batch
#define CL_ 64       // chunk length
#define NP1_ 2052    // padded N+stride
#define NBLK_ 256    // == CU count; cooperative co-residency safe at 1 blk/CU

// ---------------- ws layout (floats) ----------------
#define H_OFF    ((size_t)0)
#define P_OFF    (H_OFF + (size_t)B_*N_*C_)
#define Q_OFF    (P_OFF + (size_t)B_*N_)
#define LOK_OFF  (Q_OFF + (size_t)B_*N_)            // ints: lo | keep<<16
#define US_OFF   (LOK_OFF + (size_t)B_*N_)
#define VS_OFF   (US_OFF + (size_t)B_*N_)
#define SRT_OFF  (VS_OFF + (size_t)B_*N_)           // ints
#define SUS_OFF  (SRT_OFF + (size_t)B_*N_)          // B*NP1_
#define PVS_OFF  (SUS_OFF + (size_t)B_*NP1_)        // B*NP1_
#define SUL_OFF  (PVS_OFF + (size_t)B_*NP1_)
#define PVL_OFF  (SUL_OFF + (size_t)B_*N_*128)
#define TOTU_OFF (PVL_OFF + (size_t)B_*N_*128)
#define TOTV_OFF (TOTU_OFF + (size_t)B_*NCH_*128)
#define MPART_OFF (TOTV_OFF + (size_t)B_*NCH_*128)  // 256*128

union SMem {
  struct { float Wl[64 * 128]; float xl[64 * 68];
           float al[256]; float wa1[128]; float wa2[128]; } g;          // 51 KB
  struct { float ql[N_]; float pl[N_]; } r;                             // 16 KB
  struct { float hl[CL_][128]; float ul[CL_]; float vl[CL_]; int sl[CL_];
           float2 sa[256]; float2 sb[256]; } s;                         // 37 KB
  struct { float CSU[(NCH_ + 1) * 128]; float CPV[(NCH_ + 1) * 128];
           float mr[128]; float A[64]; float Bv[64]; float invD[64];
           int lo[64]; int keep[64]; float res[64 * 129]; } o;          // 67 KB
};

__global__ __launch_bounds__(512, 4) void k_all(
    const float* __restrict__ x, const float* __restrict__ W,
    const float* __restrict__ a, float* __restrict__ out,
    float* __restrict__ h, float* __restrict__ p, float* __restrict__ q,
    int* __restrict__ lok, float* __restrict__ u_s, float* __restrict__ v_s,
    int* __restrict__ srt, float* __restrict__ SUS, float* __restrict__ PVS,
    float* __restrict__ SUl, float* __restrict__ PVl,
    float* __restrict__ totU, float* __restrict__ totV,
    float* __restrict__ mpart, int phase) {
  __shared__ SMem sm;
  cg::grid_group grid = cg::this_grid();
  const int blk = blockIdx.x, t = threadIdx.x;
  const bool all = (phase < 0);

  // ================= P0: pq + gemm(h) + mpart (64 rows/block) ==============
  if (all || phase == 0) {
    const int r0 = blk * 64;
    if (t < 256) sm.g.al[t] = a[t];
    __syncthreads();
    if (t < 128) {   // wa = W @ a_half (row dots)
      const float* Wr = W + (size_t)t * 128;
      float s1 = 0.f, s2 = 0.f;
#pragma unroll
      for (int j = 0; j < 128; j += 4) {
        float4 wv = *(const float4*)(Wr + j);
        s1 = fmaf(wv.x, sm.g.al[j + 0], s1);
        s1 = fmaf(wv.y, sm.g.al[j + 1], s1);
        s1 = fmaf(wv.z, sm.g.al[j + 2], s1);
        s1 = fmaf(wv.w, sm.g.al[j + 3], s1);
        s2 = fmaf(wv.x, sm.g.al[128 + j + 0], s2);
        s2 = fmaf(wv.y, sm.g.al[128 + j + 1], s2);
        s2 = fmaf(wv.z, sm.g.al[128 + j + 2], s2);
        s2 = fmaf(wv.w, sm.g.al[128 + j + 3], s2);
      }
      sm.g.wa1[t] = s1; sm.g.wa2[t] = s2;
    }
    __syncthreads();
    {  // pq: 8 lanes/row, 16 floats/lane
      const int row = t >> 3, part = t & 7;
      const float* xr = x + (size_t)(r0 + row) * 128 + part * 16;
      const float* w1 = sm.g.wa1 + part * 16;
      const float* w2 = sm.g.wa2 + part * 16;
      float sp = 0.f, sq = 0.f;
#pragma unroll
      for (int i = 0; i < 4; ++i) {
        float4 xv = *(const float4*)(xr + 4 * i);
        float4 w1v = *(const float4*)(w1 + 4 * i);
        float4 w2v = *(const float4*)(w2 + 4 * i);
        sp = fmaf(xv.x, w1v.x, sp); sp = fmaf(xv.y, w1v.y, sp);
        sp = fmaf(xv.z, w1v.z, sp); sp = fmaf(xv.w, w1v.w, sp);
        sq = fmaf(xv.x, w2v.x, sq); sq = fmaf(xv.y, w2v.y, sq);
        sq = fmaf(xv.z, w2v.z, sq); sq = fmaf(xv.w, w2v.w, sq);
      }
      sp += __shfl_xor(sp, 1, 64); sp += __shfl_xor(sp, 2, 64); sp += __shfl_xor(sp, 4, 64);
      sq += __shfl_xor(sq, 1, 64); sq += __shfl_xor(sq, 2, 64); sq += __shfl_xor(sq, 4, 64);
      if (part == 0) { p[r0 + row] = sp; q[r0 + row] = sq; }
    }
    // gemm (R16-proven: 256 compute threads 4x8, all 512 stage)
    const int cg2 = t & 15, rp = (t >> 4) & 15;
    const bool act = t < 256;
    float acc[4][8];
#pragma unroll
    for (int r = 0; r < 4; ++r)
#pragma unroll
      for (int j = 0; j < 8; ++j) acc[r][j] = 0.f;
    for (int kc = 0; kc < 2; ++kc) {
      __syncthreads();
      const float4* W4 = (const float4*)(W + (size_t)kc * 64 * 128);
      float4* Wl4 = (float4*)sm.g.Wl;
#pragma unroll
      for (int i = 0; i < 4; ++i) Wl4[t + 512 * i] = W4[t + 512 * i];
#pragma unroll
      for (int i = 0; i < 2; ++i) {
        int idx = t + 512 * i;
        int row = idx >> 4, c4i = idx & 15;
        float4 v = *(const float4*)(x + (size_t)(r0 + row) * 128 + kc * 64 + c4i * 4);
        ((float4*)sm.g.xl)[row * 17 + c4i] = v;
      }
      __syncthreads();
      if (act) {
        for (int k = 0; k < 64; ++k) {
          const float4* Wr = (const float4*)(sm.g.Wl + k * 128);
          float4 w0 = Wr[cg2];
          float4 w1 = Wr[cg2 + 16];
#pragma unroll
          for (int r = 0; r < 4; ++r) {
            float xv = sm.g.xl[(4 * rp + r) * 68 + k];
            acc[r][0] = fmaf(xv, w0.x, acc[r][0]);
            acc[r][1] = fmaf(xv, w0.y, acc[r][1]);
            acc[r][2] = fmaf(xv, w0.z, acc[r][2]);
            acc[r][3] = fmaf(xv, w0.w, acc[r][3]);
            acc[r][4] = fmaf(xv, w1.x, acc[r][4]);
            acc[r][5] = fmaf(xv, w1.y, acc[r][5]);
            acc[r][6] = fmaf(xv, w1.z, acc[r][6]);
            acc[r][7] = fmaf(xv, w1.w, acc[r][7]);
          }
        }
      }
    }
    const int c0 = 4 * cg2, c1 = 4 * cg2 + 64;
    size_t hb = (size_t)r0 * 128;
    __syncthreads();               // xl reads done before scratch reuse
    float* scratch = sm.g.xl;      // 16 x 128 four-row sums
    if (act) {
#pragma unroll
      for (int r = 0; r < 4; ++r) {
        int row = 4 * rp + r;
        *(float4*)(h + hb + (size_t)row * 128 + c0) =
            make_float4(acc[r][0], acc[r][1], acc[r][2], acc[r][3]);
        *(float4*)(h + hb + (size_t)row * 128 + c1) =
            make_float4(acc[r][4], acc[r][5], acc[r][6], acc[r][7]);
      }
#pragma unroll
      for (int j = 0; j < 4; ++j) {
        scratch[rp * 128 + c0 + j] = acc[0][j] + acc[1][j] + acc[2][j] + acc[3][j];
        scratch[rp * 128 + c1 + j] = acc[0][4 + j] + acc[1][4 + j] + acc[2][4 + j] + acc[3][4 + j];
      }
    }
    __syncthreads();
    if (t < 128) {
      float s = 0.f;
#pragma unroll
      for (int rr = 0; rr < 16; ++rr) s += scratch[rr * 128 + t];
      mpart[(size_t)blk * 128 + t] = s;
    }
  }
  if (all) grid.sync(); else if (phase == 0) return;

  // ================= P1: rank (64 rows/block, 8 lanes/row) =================
  if (all || phase == 1) {
    const int b = blk >> 5, i0 = (blk & 31) * 64;
    ((float4*)sm.r.ql)[t] = ((const float4*)(q + (size_t)b * N_))[t];
    ((float4*)sm.r.pl)[t] = ((const float4*)(p + (size_t)b * N_))[t];
    __syncthreads();
    const int row = t >> 3, s8 = t & 7;
    const int i = i0 + row;
    const float qi = sm.r.ql[i], pi = sm.r.pl[i];
    const float negpi = -pi;
    int qr = 0, lo = 0, pr = 0;
    for (int g2 = s8; g2 < 512; g2 += 8) {
      float4 qj = ((const float4*)sm.r.ql)[g2];
      float4 pj = ((const float4*)sm.r.pl)[g2];
      const int j0 = 4 * g2;
      qr += (qj.x < qi || (qj.x == qi && (j0 + 0) < i)) ? 1 : 0;
      qr += (qj.y < qi || (qj.y == qi && (j0 + 1) < i)) ? 1 : 0;
      qr += (qj.z < qi || (qj.z == qi && (j0 + 2) < i)) ? 1 : 0;
      qr += (qj.w < qi || (qj.w == qi && (j0 + 3) < i)) ? 1 : 0;
      lo += (qj.x < negpi) ? 1 : 0;
      lo += (qj.y < negpi) ? 1 : 0;
      lo += (qj.z < negpi) ? 1 : 0;
      lo += (qj.w < negpi) ? 1 : 0;
      pr += (pj.x > pi || (pj.x == pi && (j0 + 0) < i)) ? 1 : 0;
      pr += (pj.y > pi || (pj.y == pi && (j0 + 1) < i)) ? 1 : 0;
      pr += (pj.z > pi || (pj.z == pi && (j0 + 2) < i)) ? 1 : 0;
      pr += (pj.w > pi || (pj.w == pi && (j0 + 3) < i)) ? 1 : 0;
    }
    qr += __shfl_xor(qr, 1, 64); qr += __shfl_xor(qr, 2, 64); qr += __shfl_xor(qr, 4, 64);
    lo += __shfl_xor(lo, 1, 64); lo += __shfl_xor(lo, 2, 64); lo += __shfl_xor(lo, 4, 64);
    pr += __shfl_xor(pr, 1, 64); pr += __shfl_xor(pr, 2, 64); pr += __shfl_xor(pr, 4, 64);
    if (s8 == 0) {
      u_s[(size_t)b * N_ + qr] = __expf(qi);
      v_s[(size_t)b * N_ + qr] = __expf(0.01f * qi);
      srt[(size_t)b * N_ + qr] = i;
      lok[(size_t)b * N_ + i] = lo | ((pr < TOPK_) ? 0x10000 : 0);
    }
  }
  if (all) grid.sync(); else if (phase == 1) return;

  // ===== P2: chunk scans (all blocks) + scalar scans (folded, blocks 0..7) ==
  if (all || phase == 2) {
    const int b = blk >> 5, ch = blk & 31;
    const int base = b * N_ + ch * CL_;
    if (t < CL_) { sm.s.ul[t] = u_s[base + t]; sm.s.vl[t] = v_s[base + t]; sm.s.sl[t] = srt[base + t]; }
    __syncthreads();
    {
      const int c4 = t & 31, rr = t >> 5;   // rr in 0..15
#pragma unroll
      for (int i = 0; i < 4; ++i) {
        int tt = rr + 16 * i;
        float4 v = *(const float4*)(h + ((size_t)b * N_ + sm.s.sl[tt]) * 128 + 4 * c4);
        *(float4*)(&sm.s.hl[tt][4 * c4]) = v;
      }
    }
    __syncthreads();
    if (blk < B_) {
      // scalar suffix/prefix scans for batch b2 = blk (block-uniform branch;
      // barriers legal — counts differ only ACROSS blocks)
      const int b2 = blk;
      float4 ua = {}, ub = {}, wa = {}, wb = {};
      float su = 0.f, sw = 0.f;
      if (t < 256) {
        ua = ((const float4*)(u_s + (size_t)b2 * N_))[2 * t];
        ub = ((const float4*)(u_s + (size_t)b2 * N_))[2 * t + 1];
        wa = ((const float4*)(v_s + (size_t)b2 * N_))[2 * t];
        wb = ((const float4*)(v_s + (size_t)b2 * N_))[2 * t + 1];
        su = ua.x + ua.y + ua.z + ua.w + ub.x + ub.y + ub.z + ub.w;
        sw = wa.x + wa.y + wa.z + wa.w + wb.x + wb.y + wb.z + wb.w;
        sm.s.sa[t] = make_float2(su, sw);
      }
      __syncthreads();
      float2* cur = sm.s.sa; float2* nxt = sm.s.sb;
      for (int off = 1; off < 256; off <<= 1) {
        if (t < 256) {
          float2 vv = cur[t];
          if (t >= off) { float2 o2 = cur[t - off]; vv.x += o2.x; vv.y += o2.y; }
          nxt[t] = vv;
        }
        __syncthreads();
        float2* tmp = cur; cur = nxt; nxt = tmp;
      }
      if (t < 256) {
        float2 incl = cur[t];
        float2 tot = cur[255];
        float exclU = incl.x - su, exclW = incl.y - sw;
        float s0 = tot.x - exclU;
        float s1 = s0 - ua.x, s2 = s1 - ua.y, s3 = s2 - ua.z;
        float s4 = s3 - ua.w, s5 = s4 - ub.x, s6 = s5 - ub.y, s7 = s6 - ub.z;
        float p0 = exclW;
        float p1 = p0 + wa.x, p2 = p1 + wa.y, p3 = p2 + wa.z;
        float p4 = p3 + wa.w, p5 = p4 + wb.x, p6 = p5 + wb.y, p7 = p6 + wb.z;
        float* Sb = SUS + (size_t)b2 * NP1_ + 8 * t;
        float* Pb = PVS + (size_t)b2 * NP1_ + 8 * t;
        *(float4*)(Sb) = make_float4(s0, s1, s2, s3);
        *(float4*)(Sb + 4) = make_float4(s4, s5, s6, s7);
        *(float4*)(Pb) = make_float4(p0, p1, p2, p3);
        *(float4*)(Pb + 4) = make_float4(p4, p5, p6, p7);
        if (t == 255) {
          SUS[(size_t)b2 * NP1_ + N_] = 0.f;
          PVS[(size_t)b2 * NP1_ + N_] = tot.y;
        }
      }
    }
    // chunk-local scans (sa/sb disjoint from hl/ul/vl in struct s)
    if (t < 128) {
      const int c = t;
      float run = 0.f;
      for (int tt = CL_ - 1; tt >= 0; --tt) {
        run = fmaf(sm.s.ul[tt], sm.s.hl[tt][c], run);
        SUl[((size_t)(base + tt)) * 128 + c] = run;
      }
      totU[(size_t)(b * NCH_ + ch) * 128 + c] = run;
    } else if (t < 256) {
      const int c = t - 128;
      float run2 = 0.f;
      for (int tt = 0; tt < CL_; ++tt) {
        PVl[((size_t)(base + tt)) * 128 + c] = run2;
        run2 = fmaf(sm.s.vl[tt], sm.s.hl[tt][c], run2);
      }
      totV[(size_t)(b * NCH_ + ch) * 128 + c] = run2;
    }
  }
  if (all) grid.sync(); else if (phase == 2) return;

  // ================= P3: tables + combine + transposed store ===============
  if (all || phase == 3) {
    const int b = blk >> 5, tile = blk & 31;
    const int i0 = tile * 64;
    if (t < 128) {
      float ms = 0.f;
#pragma unroll
      for (int j = 0; j < 32; ++j) ms += mpart[(size_t)(b * 32 + j) * 128 + t];
      sm.o.mr[t] = fmaxf(ms * (1.0f / (float)N_), 0.f);
      float s = 0.f;
      sm.o.CSU[NCH_ * 128 + t] = 0.f;
      for (int cc = NCH_ - 1; cc >= 0; --cc) {
        s += totU[(size_t)(b * NCH_ + cc) * 128 + t];
        sm.o.CSU[cc * 128 + t] = s;
      }
    } else if (t < 256) {
      const int c2 = t - 128;
      float s2 = 0.f;
      for (int cc = 0; cc < NCH_; ++cc) {
        sm.o.CPV[cc * 128 + c2] = s2;
        s2 += totV[(size_t)(b * NCH_ + cc) * 128 + c2];
      }
      sm.o.CPV[NCH_ * 128 + c2] = s2;
    }
    __syncthreads();
    if (t < 64) {
      float pv = p[b * N_ + i0 + t];
      int lk = lok[(size_t)b * N_ + i0 + t];
      sm.o.keep[t] = (lk >> 16) & 1;
      int lo = lk & 0xFFFF;
      sm.o.lo[t] = lo;
      float A = __expf(pv), Bv = __expf(0.01f * pv);
      sm.o.A[t] = A; sm.o.Bv[t] = Bv;
      float sus = SUS[(size_t)b * NP1_ + lo];
      float pvs = PVS[(size_t)b * NP1_ + lo];
      sm.o.invD[t] = 1.0f / fmaf(A, sus, Bv * pvs);
    }
    __syncthreads();
    const int quarter = t >> 7, c = t & 127;
#pragma unroll 4
    for (int m = 0; m < 16; ++m) {
      int ii = 4 * m + quarter;
      float outv;
      if (sm.o.keep[ii]) {
        int lo = sm.o.lo[ii];
        float A = sm.o.A[ii], Bv = sm.o.Bv[ii];
        float suc, pvc;
        if (lo < N_) {
          int chn = lo >> 6;   // / CL_
          size_t ro = ((size_t)(b * N_ + lo)) * 128;
          suc = SUl[ro + c] + sm.o.CSU[(chn + 1) * 128 + c];
          pvc = PVl[ro + c] + sm.o.CPV[chn * 128 + c];
        } else {
          suc = 0.f;
          pvc = sm.o.CPV[NCH_ * 128 + c];
        }
        outv = fmaxf(fmaf(A, suc, Bv * pvc) * sm.o.invD[ii], 0.f);
      } else {
        outv = sm.o.mr[c];
      }
      sm.o.res[ii * 129 + c] = outv;
    }
    __syncthreads();
    // out[b][cc][i0+ii4..] = res[ii4..][cc]; 2048 float4 / 512 thr = 4 passes
#pragma unroll
    for (int pass = 0; pass < 4; ++pass) {
      int idx = pass * 512 + t;
      int cc = idx >> 4;
      int ii4 = (idx & 15) * 4;
      float4 v;
      v.x = sm.o.res[(ii4 + 0) * 129 + cc];
      v.y = sm.o.res[(ii4 + 1) * 129 + cc];
      v.z = sm.o.res[(ii4 + 2) * 129 + cc];
      v.w = sm.o.res[(ii4 + 3) * 129 + cc];
      *(float4*)(out + ((size_t)(b * C_ + cc)) * N_ + i0 + ii4) = v;
    }
  }
}

extern "C" void kernel_launch(void* const* d_in, const int* in_sizes, int n_in,
                              void* d_out, int out_size, void* d_ws, size_t ws_size,
                              hipStream_t stream) {
  (void)in_sizes; (void)n_in; (void)out_size; (void)ws_size;
  const float* x = (const float*)d_in[0];
  const float* W = (const float*)d_in[1];
  const float* a = (const float*)d_in[2];
  // d_in[3] (GL) is provably unused: adj > 0 everywhere.
  float* out = (float*)d_out;
  float* ws = (float*)d_ws;

  float* h    = ws + H_OFF;
  float* p    = ws + P_OFF;
  float* q    = ws + Q_OFF;
  int*   lok  = (int*)(ws + LOK_OFF);
  float* u_s  = ws + US_OFF;
  float* v_s  = ws + VS_OFF;
  int*   srt  = (int*)(ws + SRT_OFF);
  float* SUS  = ws + SUS_OFF;
  float* PVS  = ws + PVS_OFF;
  float* SUl  = ws + SUL_OFF;
  float* PVl  = ws + PVL_OFF;
  float* totU = ws + TOTU_OFF;
  float* totV = ws + TOTV_OFF;
  float* mpart = ws + MPART_OFF;

  int ph_all = -1;
  void* args[] = {
    (void*)&x, (void*)&W, (void*)&a, (void*)&out,
    (void*)&h, (void*)&p, (void*)&q, (void*)&lok,
    (void*)&u_s, (void*)&v_s, (void*)&srt, (void*)&SUS, (void*)&PVS,
    (void*)&SUl, (void*)&PVl, (void*)&totU, (void*)&totV, (void*)&mpart,
    (void*)&ph_all
  };
  hipError_t err = hipLaunchCooperativeKernel((const void*)k_all, dim3(NBLK_),
                                              dim3(512), args, 0, stream);
  if (err != hipSuccess) {
    (void)hipGetLastError();  // clear; fall back to per-phase launches (==R16)
    for (int ph = 0; ph < 4; ++ph) {
      hipLaunchKernelGGL(k_all, dim3(NBLK_), dim3(512), 0, stream,
                         x, W, a, out, h, p, q, lok, u_s, v_s, srt,
                         SUS, PVS, SUl, PVl, totU, totV, mpart, ph);
    }
  }
}

// Round 13
// 125.016 us; speedup vs baseline: 1.6866x; 1.6866x over previous
//
#include <hip/hip_runtime.h>
#include <math.h>

// Problem constants (fixed by setup_inputs): B=8, N=2048, C=128, TOP_K=512
// Algebraic structure (verified passing since R1):
//  - adj = softmax(relu(GL GL^T)) + I > 0 everywhere  => att == e, GL unused.
//  - e[b,i,j] = leaky_relu(p_i + q_j) monotone in p_i => keep iff
//    (p_i, -i) >= 512th largest; unselected rows => relu(mean_j h[b,j,:]).
//  - exp(leaky_relu(p+q)) separates at q >= -p; sorted-q order =>
//    suffix/prefix sums per row (boundary lo_i). p=x@(W@a1), q=x@(W@a2).
//
// Journal: R11 111.2 -> R13 106.3 -> R16 104.8 BEST -> R17/R18 linearity
// detour (k_out 45.2us latency-bound) -> R20 coop silently rejected ->
// R21 coop ran correct but 131.6us (1 blk/CU; grid.sync >> launch cost) ->
// R22/R23 = the 3-launch fusion below; both bench attempts died at the
// BROKER ("container failed twice", rounds 11+12 — never reached pytest).
// TIMELINE MODEL: fill ~42us + ~10us/launch + kernels. R16 = 42+40+17.
// R24: same experiment, textually perturbed (kernel renamed, comments
//   reworded -> new source hash dodges any cached-artifact infra failure).
//   Audit x3: barriers block-uniform, LDS union 49.4KB, all bounds OK.
//   3 launches: the gemm launch also computes the FULL-batch GEMV p,q
//   into LDS per block (bit-identical across a batch's 32 blocks ->
//   consistent ranks; x L2-hot; 8-lane coalesced; ~8us wall) and ranks
//   its own 64 rows. k_scan / k_out = R16-proven verbatim.

#define B_ 8
#define N_ 2048
#define C_ 128
#define TOPK_ 512
#define NCH_ 32      // chunks per batch
#define CL_ 64       // chunk length
#define NP1_ 2052    // padded N+stride
#define GRID1_ 256   // one block per (batch, 64-row tile)

// ---------------- ws layout (floats) ----------------
#define H_OFF    ((size_t)0)
#define P_OFF    (H_OFF + (size_t)B_*N_*C_)
#define LOK_OFF  (P_OFF + (size_t)B_*N_)            // ints: lo | keep<<16
#define US_OFF   (LOK_OFF + (size_t)B_*N_)
#define VS_OFF   (US_OFF + (size_t)B_*N_)
#define SRT_OFF  (VS_OFF + (size_t)B_*N_)           // ints
#define SUS_OFF  (SRT_OFF + (size_t)B_*N_)          // B*NP1_
#define PVS_OFF  (SUS_OFF + (size_t)B_*NP1_)        // B*NP1_
#define SUL_OFF  (PVS_OFF + (size_t)B_*NP1_)
#define PVL_OFF  (SUL_OFF + (size_t)B_*N_*128)
#define TOTU_OFF (PVL_OFF + (size_t)B_*N_*128)
#define TOTV_OFF (TOTU_OFF + (size_t)B_*NCH_*128)
#define MPART_OFF (TOTV_OFF + (size_t)B_*NCH_*128)  // 256*128

// ------- K1: h-gemm + mpart, then full-batch GEMV (p,q), then rank ---------
// 256 blocks x 512 threads; block (b,tile) owns h-rows r0..r0+63.
__global__ __launch_bounds__(512, 4) void k_gvr(
    const float* __restrict__ x, const float* __restrict__ W,
    const float* __restrict__ a,
    float* __restrict__ h, float* __restrict__ mpart, float* __restrict__ p,
    float* __restrict__ u_s, float* __restrict__ v_s,
    int* __restrict__ srt, int* __restrict__ lok) {
  union SM {
    struct { float Wl[64 * 128]; float xl[64 * 68]; } g;            // 49.4 KB
    struct { float ql[N_]; float pl[N_];
             float wa1[128]; float wa2[128]; float al[256]; } r;    // 18 KB
  };
  __shared__ SM sm;
  const int blk = blockIdx.x, t = threadIdx.x;
  const int b = blk >> 5, tile = blk & 31;
  const int r0 = blk * 64;

  // ---------- phase A: gemm h (256 compute threads 4x8; all 512 stage) -----
  const int cg2 = t & 15, rp = (t >> 4) & 15;
  const bool act = t < 256;
  float acc[4][8];
#pragma unroll
  for (int r = 0; r < 4; ++r)
#pragma unroll
    for (int j = 0; j < 8; ++j) acc[r][j] = 0.f;
  for (int kc = 0; kc < 2; ++kc) {
    __syncthreads();
    const float4* W4 = (const float4*)(W + (size_t)kc * 64 * 128);
    float4* Wl4 = (float4*)sm.g.Wl;
#pragma unroll
    for (int i = 0; i < 4; ++i) Wl4[t + 512 * i] = W4[t + 512 * i];
#pragma unroll
    for (int i = 0; i < 2; ++i) {
      int idx = t + 512 * i;
      int row = idx >> 4, c4i = idx & 15;
      float4 v = *(const float4*)(x + (size_t)(r0 + row) * 128 + kc * 64 + c4i * 4);
      ((float4*)sm.g.xl)[row * 17 + c4i] = v;
    }
    __syncthreads();
    if (act) {
      for (int k = 0; k < 64; ++k) {
        const float4* Wr = (const float4*)(sm.g.Wl + k * 128);
        float4 w0 = Wr[cg2];
        float4 w1 = Wr[cg2 + 16];
#pragma unroll
        for (int r = 0; r < 4; ++r) {
          float xv = sm.g.xl[(4 * rp + r) * 68 + k];
          acc[r][0] = fmaf(xv, w0.x, acc[r][0]);
          acc[r][1] = fmaf(xv, w0.y, acc[r][1]);
          acc[r][2] = fmaf(xv, w0.z, acc[r][2]);
          acc[r][3] = fmaf(xv, w0.w, acc[r][3]);
          acc[r][4] = fmaf(xv, w1.x, acc[r][4]);
          acc[r][5] = fmaf(xv, w1.y, acc[r][5]);
          acc[r][6] = fmaf(xv, w1.z, acc[r][6]);
          acc[r][7] = fmaf(xv, w1.w, acc[r][7]);
        }
      }
    }
  }
  {
    const int c0 = 4 * cg2, c1 = 4 * cg2 + 64;
    size_t hb = (size_t)r0 * 128;
    __syncthreads();               // all xl reads done before scratch reuse
    float* scratch = sm.g.xl;      // 16 x 128 per-thread-group row sums
    if (act) {
#pragma unroll
      for (int r = 0; r < 4; ++r) {
        int row = 4 * rp + r;
        *(float4*)(h + hb + (size_t)row * 128 + c0) =
            make_float4(acc[r][0], acc[r][1], acc[r][2], acc[r][3]);
        *(float4*)(h + hb + (size_t)row * 128 + c1) =
            make_float4(acc[r][4], acc[r][5], acc[r][6], acc[r][7]);
      }
#pragma unroll
      for (int j = 0; j < 4; ++j) {
        scratch[rp * 128 + c0 + j] = acc[0][j] + acc[1][j] + acc[2][j] + acc[3][j];
        scratch[rp * 128 + c1 + j] = acc[0][4 + j] + acc[1][4 + j] + acc[2][4 + j] + acc[3][4 + j];
      }
    }
    __syncthreads();
    if (t < 128) {
      float s = 0.f;
#pragma unroll
      for (int rr = 0; rr < 16; ++rr) s += scratch[rr * 128 + t];
      mpart[(size_t)blk * 128 + t] = s;
    }
  }
  __syncthreads();   // gemm LDS region dead; union switches to .r

  // ---------- phase B: wa = W@a halves; p,q for the whole batch ------------
  if (t < 256) sm.r.al[t] = a[t];
  __syncthreads();
  if (t < 128) {   // row dots of W (L2-hot after phase A)
    const float* Wr = W + (size_t)t * 128;
    float s1 = 0.f, s2 = 0.f;
#pragma unroll
    for (int j = 0; j < 128; j += 4) {
      float4 wv = *(const float4*)(Wr + j);
      s1 = fmaf(wv.x, sm.r.al[j + 0], s1);
      s1 = fmaf(wv.y, sm.r.al[j + 1], s1);
      s1 = fmaf(wv.z, sm.r.al[j + 2], s1);
      s1 = fmaf(wv.w, sm.r.al[j + 3], s1);
      s2 = fmaf(wv.x, sm.r.al[128 + j + 0], s2);
      s2 = fmaf(wv.y, sm.r.al[128 + j + 1], s2);
      s2 = fmaf(wv.z, sm.r.al[128 + j + 2], s2);
      s2 = fmaf(wv.w, sm.r.al[128 + j + 3], s2);
    }
    sm.r.wa1[t] = s1; sm.r.wa2[t] = s2;
  }
  __syncthreads();
  {
    // 8 lanes/row, 64 rows/pass, 32 passes == all 2048 rows of batch b.
    // Identical code+inputs in all 32 blocks of a batch -> bit-identical
    // p,q -> consistent ranks. x rows are L2-hot from phase A staging.
    const int row8 = t >> 3, part = t & 7;
    const float* xb = x + (size_t)b * N_ * 128;
    const float* w1 = sm.r.wa1 + part * 16;
    const float* w2 = sm.r.wa2 + part * 16;
    for (int pass = 0; pass < 32; ++pass) {
      const int r = pass * 64 + row8;
      const float* xr = xb + (size_t)r * 128 + part * 16;
      float sp = 0.f, sq = 0.f;
#pragma unroll
      for (int i2 = 0; i2 < 4; ++i2) {
        float4 xv = *(const float4*)(xr + 4 * i2);
        float4 w1v = *(const float4*)(w1 + 4 * i2);
        float4 w2v = *(const float4*)(w2 + 4 * i2);
        sp = fmaf(xv.x, w1v.x, sp); sp = fmaf(xv.y, w1v.y, sp);
        sp = fmaf(xv.z, w1v.z, sp); sp = fmaf(xv.w, w1v.w, sp);
        sq = fmaf(xv.x, w2v.x, sq); sq = fmaf(xv.y, w2v.y, sq);
        sq = fmaf(xv.z, w2v.z, sq); sq = fmaf(xv.w, w2v.w, sq);
      }
      sp += __shfl_xor(sp, 1, 64); sp += __shfl_xor(sp, 2, 64); sp += __shfl_xor(sp, 4, 64);
      sq += __shfl_xor(sq, 1, 64); sq += __shfl_xor(sq, 2, 64); sq += __shfl_xor(sq, 4, 64);
      if (part == 0) {
        sm.r.pl[r] = sp;
        sm.r.ql[r] = sq;
        if (tile == 0) p[(size_t)b * N_ + r] = sp;
      }
    }
  }
  __syncthreads();

  // ---------- phase C: rank this block's 64 rows (8 lanes/row) -------------
  {
    const int i0 = tile * 64;
    const int row = t >> 3, s8 = t & 7;
    const int i = i0 + row;
    const float qi = sm.r.ql[i], pi = sm.r.pl[i];
    const float negpi = -pi;
    int qr = 0, lo = 0, pr = 0;
    for (int g2 = s8; g2 < 512; g2 += 8) {
      float4 qj = ((const float4*)sm.r.ql)[g2];
      float4 pj = ((const float4*)sm.r.pl)[g2];
      const int j0 = 4 * g2;
      qr += (qj.x < qi || (qj.x == qi && (j0 + 0) < i)) ? 1 : 0;
      qr += (qj.y < qi || (qj.y == qi && (j0 + 1) < i)) ? 1 : 0;
      qr += (qj.z < qi || (qj.z == qi && (j0 + 2) < i)) ? 1 : 0;
      qr += (qj.w < qi || (qj.w == qi && (j0 + 3) < i)) ? 1 : 0;
      lo += (qj.x < negpi) ? 1 : 0;
      lo += (qj.y < negpi) ? 1 : 0;
      lo += (qj.z < negpi) ? 1 : 0;
      lo += (qj.w < negpi) ? 1 : 0;
      pr += (pj.x > pi || (pj.x == pi && (j0 + 0) < i)) ? 1 : 0;
      pr += (pj.y > pi || (pj.y == pi && (j0 + 1) < i)) ? 1 : 0;
      pr += (pj.z > pi || (pj.z == pi && (j0 + 2) < i)) ? 1 : 0;
      pr += (pj.w > pi || (pj.w == pi && (j0 + 3) < i)) ? 1 : 0;
    }
    qr += __shfl_xor(qr, 1, 64); qr += __shfl_xor(qr, 2, 64); qr += __shfl_xor(qr, 4, 64);
    lo += __shfl_xor(lo, 1, 64); lo += __shfl_xor(lo, 2, 64); lo += __shfl_xor(lo, 4, 64);
    pr += __shfl_xor(pr, 1, 64); pr += __shfl_xor(pr, 2, 64); pr += __shfl_xor(pr, 4, 64);
    if (s8 == 0) {
      u_s[(size_t)b * N_ + qr] = __expf(qi);
      v_s[(size_t)b * N_ + qr] = __expf(0.01f * qi);
      srt[(size_t)b * N_ + qr] = i;
      lok[(size_t)b * N_ + i] = lo | ((pr < TOPK_) ? 0x10000 : 0);
    }
  }
}

// ------- K2: chunk scans (blocks 0..255) + scalar scans (256..263) ---------
// R16-proven verbatim.
__global__ __launch_bounds__(256) void k_scan(const float* __restrict__ h,
                                              const float* __restrict__ u_s,
                                              const float* __restrict__ v_s,
                                              const int* __restrict__ srt,
                                              float* __restrict__ SUl,
                                              float* __restrict__ PVl,
                                              float* __restrict__ totU,
                                              float* __restrict__ totV,
                                              float* __restrict__ SUS,
                                              float* __restrict__ PVS) {
  __shared__ float hl[CL_][128];   // 32 KB (chunk blocks)
  __shared__ float ul[CL_], vl[CL_];
  __shared__ int sl[CL_];
  __shared__ float2 sa[256], sb[256];  // scalar-scan blocks
  const int t = threadIdx.x;
  if (blockIdx.x >= 256) {
    const int b = blockIdx.x - 256;
    float4 ua = ((const float4*)(u_s + (size_t)b * N_))[2 * t];
    float4 ub = ((const float4*)(u_s + (size_t)b * N_))[2 * t + 1];
    float4 wa = ((const float4*)(v_s + (size_t)b * N_))[2 * t];
    float4 wb = ((const float4*)(v_s + (size_t)b * N_))[2 * t + 1];
    float su = ua.x + ua.y + ua.z + ua.w + ub.x + ub.y + ub.z + ub.w;
    float sw = wa.x + wa.y + wa.z + wa.w + wb.x + wb.y + wb.z + wb.w;
    sa[t] = make_float2(su, sw);
    __syncthreads();
    float2* cur = sa; float2* nxt = sb;
    for (int off = 1; off < 256; off <<= 1) {
      float2 vv = cur[t];
      if (t >= off) { float2 o = cur[t - off]; vv.x += o.x; vv.y += o.y; }
      nxt[t] = vv;
      __syncthreads();
      float2* tmp = cur; cur = nxt; nxt = tmp;
    }
    float2 incl = cur[t];
    float2 tot = cur[255];
    float exclU = incl.x - su, exclW = incl.y - sw;
    float s0 = tot.x - exclU;
    float s1 = s0 - ua.x, s2 = s1 - ua.y, s3 = s2 - ua.z;
    float s4 = s3 - ua.w, s5 = s4 - ub.x, s6 = s5 - ub.y, s7 = s6 - ub.z;
    float p0 = exclW;
    float p1 = p0 + wa.x, p2 = p1 + wa.y, p3 = p2 + wa.z;
    float p4 = p3 + wa.w, p5 = p4 + wb.x, p6 = p5 + wb.y, p7 = p6 + wb.z;
    float* Sb = SUS + (size_t)b * NP1_ + 8 * t;
    float* Pb = PVS + (size_t)b * NP1_ + 8 * t;
    *(float4*)(Sb) = make_float4(s0, s1, s2, s3);
    *(float4*)(Sb + 4) = make_float4(s4, s5, s6, s7);
    *(float4*)(Pb) = make_float4(p0, p1, p2, p3);
    *(float4*)(Pb + 4) = make_float4(p4, p5, p6, p7);
    if (t == 255) {
      SUS[(size_t)b * NP1_ + N_] = 0.f;
      PVS[(size_t)b * NP1_ + N_] = tot.y;
    }
    return;
  }
  const int b = blockIdx.x >> 5, ch = blockIdx.x & 31;
  const int base = b * N_ + ch * CL_;
  if (t < CL_) { ul[t] = u_s[base + t]; vl[t] = v_s[base + t]; sl[t] = srt[base + t]; }
  __syncthreads();
  {
    const int c4 = t & 31, rr = t >> 5;
#pragma unroll
    for (int i = 0; i < 8; ++i) {
      int tt = rr + 8 * i;
      float4 v = *(const float4*)(h + ((size_t)b * N_ + sl[tt]) * 128 + 4 * c4);
      *(float4*)(&hl[tt][4 * c4]) = v;
    }
  }
  __syncthreads();
  if (t < 128) {
    const int c = t;
    float run = 0.f;
    for (int tt = CL_ - 1; tt >= 0; --tt) {
      run = fmaf(ul[tt], hl[tt][c], run);
      SUl[((size_t)(base + tt)) * 128 + c] = run;
    }
    totU[(size_t)(b * NCH_ + ch) * 128 + c] = run;
  } else {
    const int c = t - 128;
    float run2 = 0.f;
    for (int tt = 0; tt < CL_; ++tt) {
      PVl[((size_t)(base + tt)) * 128 + c] = run2;
      run2 = fmaf(vl[tt], hl[tt][c], run2);
    }
    totV[(size_t)(b * NCH_ + ch) * 128 + c] = run2;
  }
}

// ------- K3: tables + combine + transposed store (R16-proven verbatim) -----
__global__ __launch_bounds__(256) void k_out(const float* __restrict__ p,
                                             const int* __restrict__ lok,
                                             const float* __restrict__ SUS,
                                             const float* __restrict__ PVS,
                                             const float* __restrict__ SUl,
                                             const float* __restrict__ PVl,
                                             const float* __restrict__ totU,
                                             const float* __restrict__ totV,
                                             const float* __restrict__ mpart,
                                             float* __restrict__ out) {
  __shared__ float res[64 * 129];            // 33 KB
  __shared__ float CSUs[(NCH_ + 1) * 128];   // 16.9 KB
  __shared__ float CPVs[(NCH_ + 1) * 128];   // 16.9 KB
  __shared__ float mr[128];
  __shared__ float A_s[64], B_s[64], invD[64];
  __shared__ int lo_s[64], keep_s[64];
  const int b = blockIdx.x >> 5, tile = blockIdx.x & 31;
  const int t = threadIdx.x;
  const int i0 = tile * 64;
  if (t < 128) {
    float ms = 0.f;
#pragma unroll
    for (int j = 0; j < 32; ++j) ms += mpart[(size_t)(b * 32 + j) * 128 + t];
    mr[t] = fmaxf(ms * (1.0f / (float)N_), 0.f);
    float s = 0.f;
    CSUs[NCH_ * 128 + t] = 0.f;
    for (int cc = NCH_ - 1; cc >= 0; --cc) {
      s += totU[(size_t)(b * NCH_ + cc) * 128 + t];
      CSUs[cc * 128 + t] = s;
    }
  } else {
    const int c2 = t - 128;
    float s2 = 0.f;
    for (int cc = 0; cc < NCH_; ++cc) {
      CPVs[cc * 128 + c2] = s2;
      s2 += totV[(size_t)(b * NCH_ + cc) * 128 + c2];
    }
    CPVs[NCH_ * 128 + c2] = s2;
  }
  __syncthreads();
  if (t < 64) {
    float pv = p[b * N_ + i0 + t];
    int lk = lok[(size_t)b * N_ + i0 + t];
    keep_s[t] = (lk >> 16) & 1;
    int lo = lk & 0xFFFF;
    lo_s[t] = lo;
    float A = __expf(pv), Bv = __expf(0.01f * pv);
    A_s[t] = A; B_s[t] = Bv;
    float sus = SUS[(size_t)b * NP1_ + lo];
    float pvs = PVS[(size_t)b * NP1_ + lo];
    invD[t] = 1.0f / fmaf(A, sus, Bv * pvs);
  }
  __syncthreads();
  const int half = t >> 7, c = t & 127;
#pragma unroll 4
  for (int ii2 = 0; ii2 < 64; ii2 += 2) {
    int ii = ii2 + half;
    float outv;
    if (keep_s[ii]) {
      int lo = lo_s[ii];
      float A = A_s[ii], Bv = B_s[ii];
      float suc, pvc;
      if (lo < N_) {
        int chn = lo >> 6;   // / CL_
        size_t ro = ((size_t)(b * N_ + lo)) * 128;
        suc = SUl[ro + c] + CSUs[(chn + 1) * 128 + c];
        pvc = PVl[ro + c] + CPVs[chn * 128 + c];
      } else {
        suc = 0.f;
        pvc = CPVs[NCH_ * 128 + c];
      }
      outv = fmaxf(fmaf(A, suc, Bv * pvc) * invD[ii], 0.f);
    } else {
      outv = mr[c];
    }
    res[ii * 129 + c] = outv;
  }
  __syncthreads();
#pragma unroll
  for (int pass = 0; pass < 8; ++pass) {
    int cc = (t >> 4) + pass * 16;
    int ii4 = (t & 15) * 4;
    float4 v;
    v.x = res[(ii4 + 0) * 129 + cc];
    v.y = res[(ii4 + 1) * 129 + cc];
    v.z = res[(ii4 + 2) * 129 + cc];
    v.w = res[(ii4 + 3) * 129 + cc];
    *(float4*)(out + ((size_t)(b * C_ + cc)) * N_ + i0 + ii4) = v;
  }
}

extern "C" void kernel_launch(void* const* d_in, const int* in_sizes, int n_in,
                              void* d_out, int out_size, void* d_ws, size_t ws_size,
                              hipStream_t stream) {
  (void)in_sizes; (void)n_in; (void)out_size; (void)ws_size;
  const float* x = (const float*)d_in[0];
  const float* W = (const float*)d_in[1];
  const float* a = (const float*)d_in[2];
  // d_in[3] (GL) is provably unused: adj > 0 everywhere.
  float* out = (float*)d_out;
  float* ws = (float*)d_ws;

  float* h    = ws + H_OFF;
  float* p    = ws + P_OFF;
  int*   lok  = (int*)(ws + LOK_OFF);
  float* u_s  = ws + US_OFF;
  float* v_s  = ws + VS_OFF;
  int*   srt  = (int*)(ws + SRT_OFF);
  float* SUS  = ws + SUS_OFF;
  float* PVS  = ws + PVS_OFF;
  float* SUl  = ws + SUL_OFF;
  float* PVl  = ws + PVL_OFF;
  float* totU = ws + TOTU_OFF;
  float* totV = ws + TOTV_OFF;
  float* mpart = ws + MPART_OFF;

  k_gvr<<<dim3(GRID1_), dim3(512), 0, stream>>>(x, W, a, h, mpart, p, u_s, v_s, srt, lok);
  k_scan<<<dim3(256 + B_), dim3(256), 0, stream>>>(h, u_s, v_s, srt, SUl, PVl, totU, totV, SUS, PVS);
  k_out<<<dim3(B_ * 32), dim3(256), 0, stream>>>(p, lok, SUS, PVS, SUl, PVl, totU, totV, mpart, out);
}

// Round 14
// 103.844 us; speedup vs baseline: 2.0304x; 1.2039x over previous
//
#include <hip/hip_runtime.h>
#include <math.h>

// Problem constants (fixed by setup_inputs): B=8, N=2048, C=128, TOP_K=512
// Algebraic structure (verified passing since R1):
//  - adj = softmax(relu(GL GL^T)) + I > 0 everywhere  => att == e, GL unused.
//  - e[b,i,j] = leaky_relu(p_i + q_j) monotone in p_i => mask depends only on
//    (b,i): row kept iff (p_i, -i) >= 512th largest (p, -idx).
//  - Unselected rows: softmax(all-zeros) = uniform => relu(mean_j h[b,j,:]).
//  - Kept rows: exp(leaky_relu(p+q)) separates at q >= -p into e^p e^q and
//    e^{.01p} e^{.01q}; sorted-q order => suffix/prefix sums + lo_i boundary.
//  - p = x@(W@a1), q = x@(W@a2) (R12): p,q computable without h.
//
// Journal: R11 111.2 -> R13 106.3 -> R16 104.8 BEST (this source) ->
// R17 118.5 (132KB-LDS k_out, 1 blk/CU) -> R18 140.4 (k_out 45.2us,
// L2-latency gemm at occ 20%) -> R20 coop rejected silently -> R21 coop ran
// 131.6us (1 blk/CU + grid.sync quiesce) -> R24 125.0 (k_gvr 49.9us:
// per-block full-batch GEMV re-fetched x ~4x across XCD L2s, FETCH 35.7MB).
// CONCLUSION: the 4-launch R16 structure is forced by the dependency chain
// p,q -> rank -> {srt->scan, lok->out}; replication loses to ~10us/launch,
// grid-sync costs more (R21). Floor: fill ~42 (harness, fixed) + 4x~10
// launch + ~20 kernels ~= 100-105us. R25 = byte-identical R16 revert.

#define B_ 8
#define N_ 2048
#define C_ 128
#define TOPK_ 512
#define NCH_ 32      // chunks per batch
#define CL_ 64       // chunk length (NCH_*CL_ == N_)
#define NP1_ 2052    // padded N+stride, multiple of 4
#define RANKB_ 256   // rank blocks in k_fuse (32 per batch)

// ---------------- ws layout (floats) ----------------
#define H_OFF    ((size_t)0)
#define P_OFF    (H_OFF + (size_t)B_*N_*C_)
#define Q_OFF    (P_OFF + (size_t)B_*N_)
#define LOK_OFF  (Q_OFF + (size_t)B_*N_)            // ints: lo | keep<<16
#define US_OFF   (LOK_OFF + (size_t)B_*N_)
#define VS_OFF   (US_OFF + (size_t)B_*N_)
#define SRT_OFF  (VS_OFF + (size_t)B_*N_)           // ints
#define SUS_OFF  (SRT_OFF + (size_t)B_*N_)          // B*NP1_
#define PVS_OFF  (SUS_OFF + (size_t)B_*NP1_)        // B*NP1_
#define SUL_OFF  (PVS_OFF + (size_t)B_*NP1_)
#define PVL_OFF  (SUL_OFF + (size_t)B_*N_*128)
#define TOTU_OFF (PVL_OFF + (size_t)B_*N_*128)
#define TOTV_OFF (TOTU_OFF + (size_t)B_*NCH_*128)
#define MPART_OFF (TOTV_OFF + (size_t)B_*NCH_*128)  // 256*128 tile col sums

// ---------------- K0: p = x@(W a1), q = x@(W a2) ----------------
__global__ __launch_bounds__(256) void k_pq(const float* __restrict__ x,
                                            const float* __restrict__ W,
                                            const float* __restrict__ a,
                                            float* __restrict__ p,
                                            float* __restrict__ q) {
  __shared__ float al[256];
  __shared__ float wa1[128], wa2[128];
  const int t = threadIdx.x;
  const int r0 = blockIdx.x * 64;
  al[t] = a[t];
  __syncthreads();
  if (t < 128) {
    const float* Wr = W + (size_t)t * 128;
    float s1 = 0.f, s2 = 0.f;
#pragma unroll
    for (int j = 0; j < 128; j += 4) {
      float4 wv = *(const float4*)(Wr + j);
      s1 = fmaf(wv.x, al[j + 0], s1);
      s1 = fmaf(wv.y, al[j + 1], s1);
      s1 = fmaf(wv.z, al[j + 2], s1);
      s1 = fmaf(wv.w, al[j + 3], s1);
      s2 = fmaf(wv.x, al[128 + j + 0], s2);
      s2 = fmaf(wv.y, al[128 + j + 1], s2);
      s2 = fmaf(wv.z, al[128 + j + 2], s2);
      s2 = fmaf(wv.w, al[128 + j + 3], s2);
    }
    wa1[t] = s1; wa2[t] = s2;
  }
  __syncthreads();
  const int row = t >> 2, part = t & 3;   // 4 consecutive lanes per row
  const float* xr = x + (size_t)(r0 + row) * 128 + part * 32;
  const float* w1 = wa1 + part * 32;
  const float* w2 = wa2 + part * 32;
  float sp = 0.f, sq = 0.f;
#pragma unroll
  for (int i = 0; i < 8; ++i) {
    float4 xv = *(const float4*)(xr + 4 * i);
    float4 w1v = *(const float4*)(w1 + 4 * i);
    float4 w2v = *(const float4*)(w2 + 4 * i);
    sp = fmaf(xv.x, w1v.x, sp); sp = fmaf(xv.y, w1v.y, sp);
    sp = fmaf(xv.z, w1v.z, sp); sp = fmaf(xv.w, w1v.w, sp);
    sq = fmaf(xv.x, w2v.x, sq); sq = fmaf(xv.y, w2v.y, sq);
    sq = fmaf(xv.z, w2v.z, sq); sq = fmaf(xv.w, w2v.w, sq);
  }
  sp += __shfl_xor(sp, 1, 64); sp += __shfl_xor(sp, 2, 64);
  sq += __shfl_xor(sq, 1, 64); sq += __shfl_xor(sq, 2, 64);
  if (part == 0) { p[r0 + row] = sp; q[r0 + row] = sq; }
}

// ---------------- K1: fused rank (blocks 0..255) + gemm (256..511) ---------
// 512 threads. Rank block (b,tile): 64 rows; LDS-resident p[b],q[b];
// per row count qrank/lo/prank over all 2048 j; scatter u/w/srt by qrank.
// Gemm: 64 rows, 256 compute threads (4x8 each), all 512 stage.
__global__ __launch_bounds__(512, 4) void k_fuse(
    const float* __restrict__ x, const float* __restrict__ W,
    float* __restrict__ h, float* __restrict__ mpart,
    const float* __restrict__ q, const float* __restrict__ p,
    float* __restrict__ u_s, float* __restrict__ v_s,
    int* __restrict__ srt, int* __restrict__ lok) {
  union __align__(16) SMem {
    struct { float Wl[64 * 128]; float xl[64 * 68]; } g;   // 49 KB gemm
    struct { float ql[N_]; float pl[N_]; } r;              // 16 KB rank
  };
  __shared__ SMem sm;
  const int blk = blockIdx.x, t = threadIdx.x;

  if (blk < RANKB_) {
    // ================= rank path =================
    const int b = blk >> 5, tile = blk & 31;
    const int i0 = tile * 64;
    ((float4*)sm.r.ql)[t] = ((const float4*)(q + (size_t)b * N_))[t];
    ((float4*)sm.r.pl)[t] = ((const float4*)(p + (size_t)b * N_))[t];
    __syncthreads();
    const int row = t >> 3, s = t & 7;
    const int i = i0 + row;
    const float qi = sm.r.ql[i], pi = sm.r.pl[i];
    const float negpi = -pi;
    int qr = 0, lo = 0, pr = 0;
    for (int g = s; g < 512; g += 8) {
      float4 qj = ((const float4*)sm.r.ql)[g];
      float4 pj = ((const float4*)sm.r.pl)[g];
      const int j0 = 4 * g;
      qr += (qj.x < qi || (qj.x == qi && (j0 + 0) < i)) ? 1 : 0;
      qr += (qj.y < qi || (qj.y == qi && (j0 + 1) < i)) ? 1 : 0;
      qr += (qj.z < qi || (qj.z == qi && (j0 + 2) < i)) ? 1 : 0;
      qr += (qj.w < qi || (qj.w == qi && (j0 + 3) < i)) ? 1 : 0;
      lo += (qj.x < negpi) ? 1 : 0;
      lo += (qj.y < negpi) ? 1 : 0;
      lo += (qj.z < negpi) ? 1 : 0;
      lo += (qj.w < negpi) ? 1 : 0;
      pr += (pj.x > pi || (pj.x == pi && (j0 + 0) < i)) ? 1 : 0;
      pr += (pj.y > pi || (pj.y == pi && (j0 + 1) < i)) ? 1 : 0;
      pr += (pj.z > pi || (pj.z == pi && (j0 + 2) < i)) ? 1 : 0;
      pr += (pj.w > pi || (pj.w == pi && (j0 + 3) < i)) ? 1 : 0;
    }
    qr += __shfl_xor(qr, 1, 64); qr += __shfl_xor(qr, 2, 64); qr += __shfl_xor(qr, 4, 64);
    lo += __shfl_xor(lo, 1, 64); lo += __shfl_xor(lo, 2, 64); lo += __shfl_xor(lo, 4, 64);
    pr += __shfl_xor(pr, 1, 64); pr += __shfl_xor(pr, 2, 64); pr += __shfl_xor(pr, 4, 64);
    if (s == 0) {
      u_s[(size_t)b * N_ + qr] = __expf(qi);
      v_s[(size_t)b * N_ + qr] = __expf(0.01f * qi);
      srt[(size_t)b * N_ + qr] = i;
      lok[(size_t)b * N_ + i] = lo | ((pr < TOPK_) ? 0x10000 : 0);
    }
    return;
  }

  // ================= gemm path (64 rows, 256 compute threads) ==============
  float* Wl = sm.g.Wl;
  float* xl = sm.g.xl;
  const int g = blk - RANKB_;
  const int r0 = g * 64;
  const int cg = t & 15, rp = (t >> 4) & 15;  // meaningful for t<256
  const bool act = t < 256;
  float acc[4][8];
#pragma unroll
  for (int r = 0; r < 4; ++r)
#pragma unroll
    for (int j = 0; j < 8; ++j) acc[r][j] = 0.f;

  for (int kc = 0; kc < 2; ++kc) {
    __syncthreads();
    // staging: all 512 threads
    const float4* W4 = (const float4*)(W + (size_t)kc * 64 * 128);
    float4* Wl4 = (float4*)Wl;
#pragma unroll
    for (int i = 0; i < 4; ++i) Wl4[t + 512 * i] = W4[t + 512 * i];
#pragma unroll
    for (int i = 0; i < 2; ++i) {
      int idx = t + 512 * i;
      int row = idx >> 4, c4i = idx & 15;
      float4 v = *(const float4*)(x + (size_t)(r0 + row) * 128 + kc * 64 + c4i * 4);
      ((float4*)xl)[row * 17 + c4i] = v;
    }
    __syncthreads();
    if (act) {
      for (int k = 0; k < 64; ++k) {
        const float4* Wr = (const float4*)(Wl + k * 128);
        float4 w0 = Wr[cg];
        float4 w1 = Wr[cg + 16];
#pragma unroll
        for (int r = 0; r < 4; ++r) {
          float xv = xl[(4 * rp + r) * 68 + k];
          acc[r][0] = fmaf(xv, w0.x, acc[r][0]);
          acc[r][1] = fmaf(xv, w0.y, acc[r][1]);
          acc[r][2] = fmaf(xv, w0.z, acc[r][2]);
          acc[r][3] = fmaf(xv, w0.w, acc[r][3]);
          acc[r][4] = fmaf(xv, w1.x, acc[r][4]);
          acc[r][5] = fmaf(xv, w1.y, acc[r][5]);
          acc[r][6] = fmaf(xv, w1.z, acc[r][6]);
          acc[r][7] = fmaf(xv, w1.w, acc[r][7]);
        }
      }
    }
  }
  // epilogue: h stores + mean column partials (scratch = xl reuse)
  const int c0 = 4 * cg, c1 = 4 * cg + 64;
  size_t hb = (size_t)r0 * 128;
  __syncthreads();               // xl reads done before scratch reuse
  float* scratch = xl;           // 16 x 128 four-row sums
  if (act) {
#pragma unroll
    for (int r = 0; r < 4; ++r) {
      int row = 4 * rp + r;
      *(float4*)(h + hb + (size_t)row * 128 + c0) =
          make_float4(acc[r][0], acc[r][1], acc[r][2], acc[r][3]);
      *(float4*)(h + hb + (size_t)row * 128 + c1) =
          make_float4(acc[r][4], acc[r][5], acc[r][6], acc[r][7]);
    }
#pragma unroll
    for (int j = 0; j < 4; ++j) {
      scratch[rp * 128 + c0 + j] = acc[0][j] + acc[1][j] + acc[2][j] + acc[3][j];
      scratch[rp * 128 + c1 + j] = acc[0][4 + j] + acc[1][4 + j] + acc[2][4 + j] + acc[3][4 + j];
    }
  }
  __syncthreads();
  if (t < 128) {
    float s = 0.f;
#pragma unroll
    for (int rr = 0; rr < 16; ++rr) s += scratch[rr * 128 + t];
    mpart[(size_t)g * 128 + t] = s;
  }
}

// ---------------- K2: chunk scans (blocks 0..255) + scalar scans (256..263) -
__global__ __launch_bounds__(256) void k_scan(const float* __restrict__ h,
                                              const float* __restrict__ u_s,
                                              const float* __restrict__ v_s,
                                              const int* __restrict__ srt,
                                              float* __restrict__ SUl,
                                              float* __restrict__ PVl,
                                              float* __restrict__ totU,
                                              float* __restrict__ totV,
                                              float* __restrict__ SUS,
                                              float* __restrict__ PVS) {
  __shared__ float hl[CL_][128];   // 32 KB
  __shared__ float ul[CL_], vl[CL_];
  __shared__ int sl[CL_];
  __shared__ float2 sa[256], sb[256];  // scalar-scan blocks
  const int t = threadIdx.x;
  if (blockIdx.x >= 256) {
    // ---- scalar suffix/prefix scans over sorted u,w ----
    const int b = blockIdx.x - 256;
    float4 ua = ((const float4*)(u_s + (size_t)b * N_))[2 * t];
    float4 ub = ((const float4*)(u_s + (size_t)b * N_))[2 * t + 1];
    float4 wa = ((const float4*)(v_s + (size_t)b * N_))[2 * t];
    float4 wb = ((const float4*)(v_s + (size_t)b * N_))[2 * t + 1];
    float su = ua.x + ua.y + ua.z + ua.w + ub.x + ub.y + ub.z + ub.w;
    float sw = wa.x + wa.y + wa.z + wa.w + wb.x + wb.y + wb.z + wb.w;
    sa[t] = make_float2(su, sw);
    __syncthreads();
    float2* cur = sa; float2* nxt = sb;
    for (int off = 1; off < 256; off <<= 1) {
      float2 vv = cur[t];
      if (t >= off) { float2 o = cur[t - off]; vv.x += o.x; vv.y += o.y; }
      nxt[t] = vv;
      __syncthreads();
      float2* tmp = cur; cur = nxt; nxt = tmp;
    }
    float2 incl = cur[t];
    float2 tot = cur[255];
    float exclU = incl.x - su, exclW = incl.y - sw;
    float s0 = tot.x - exclU;
    float s1 = s0 - ua.x, s2 = s1 - ua.y, s3 = s2 - ua.z;
    float s4 = s3 - ua.w, s5 = s4 - ub.x, s6 = s5 - ub.y, s7 = s6 - ub.z;
    float p0 = exclW;
    float p1 = p0 + wa.x, p2 = p1 + wa.y, p3 = p2 + wa.z;
    float p4 = p3 + wa.w, p5 = p4 + wb.x, p6 = p5 + wb.y, p7 = p6 + wb.z;
    float* Sb = SUS + (size_t)b * NP1_ + 8 * t;
    float* Pb = PVS + (size_t)b * NP1_ + 8 * t;
    *(float4*)(Sb) = make_float4(s0, s1, s2, s3);
    *(float4*)(Sb + 4) = make_float4(s4, s5, s6, s7);
    *(float4*)(Pb) = make_float4(p0, p1, p2, p3);
    *(float4*)(Pb + 4) = make_float4(p4, p5, p6, p7);
    if (t == 255) {
      SUS[(size_t)b * NP1_ + N_] = 0.f;
      PVS[(size_t)b * NP1_ + N_] = tot.y;
    }
    return;
  }
  // ---- chunk-local suffix(u*h) / exclusive-prefix(w*h) ----
  const int b = blockIdx.x >> 5, ch = blockIdx.x & 31;
  const int base = b * N_ + ch * CL_;
  if (t < CL_) { ul[t] = u_s[base + t]; vl[t] = v_s[base + t]; sl[t] = srt[base + t]; }
  __syncthreads();
  {
    const int c4 = t & 31, rr = t >> 5;
#pragma unroll
    for (int i = 0; i < 8; ++i) {
      int tt = rr + 8 * i;
      float4 v = *(const float4*)(h + ((size_t)b * N_ + sl[tt]) * 128 + 4 * c4);
      *(float4*)(&hl[tt][4 * c4]) = v;
    }
  }
  __syncthreads();
  if (t < 128) {
    const int c = t;
    float run = 0.f;
    for (int tt = CL_ - 1; tt >= 0; --tt) {
      run = fmaf(ul[tt], hl[tt][c], run);
      SUl[((size_t)(base + tt)) * 128 + c] = run;
    }
    totU[(size_t)(b * NCH_ + ch) * 128 + c] = run;
  } else {
    const int c = t - 128;
    float run2 = 0.f;
    for (int tt = 0; tt < CL_; ++tt) {
      PVl[((size_t)(base + tt)) * 128 + c] = run2;
      run2 = fmaf(vl[tt], hl[tt][c], run2);
    }
    totV[(size_t)(b * NCH_ + ch) * 128 + c] = run2;
  }
}

// ---------------- K3: tables from totU/totV (LDS) + combine + store ---------
__global__ __launch_bounds__(256) void k_out(const float* __restrict__ p,
                                             const int* __restrict__ lok,
                                             const float* __restrict__ SUS,
                                             const float* __restrict__ PVS,
                                             const float* __restrict__ SUl,
                                             const float* __restrict__ PVl,
                                             const float* __restrict__ totU,
                                             const float* __restrict__ totV,
                                             const float* __restrict__ mpart,
                                             float* __restrict__ out) {
  __shared__ float res[64 * 129];            // 33 KB
  __shared__ float CSUs[(NCH_ + 1) * 128];   // 16.9 KB
  __shared__ float CPVs[(NCH_ + 1) * 128];   // 16.9 KB
  __shared__ float mr[128];
  __shared__ float A_s[64], B_s[64], invD[64];
  __shared__ int lo_s[64], keep_s[64];
  const int b = blockIdx.x >> 5, tile = blockIdx.x & 31;
  const int t = threadIdx.x;
  const int i0 = tile * 64;
  if (t < 128) {
    // mean of h columns from mpart (L2-hot) + cross-chunk suffix table
    float ms = 0.f;
#pragma unroll
    for (int j = 0; j < 32; ++j) ms += mpart[(size_t)(b * 32 + j) * 128 + t];
    mr[t] = fmaxf(ms * (1.0f / (float)N_), 0.f);
    float s = 0.f;
    CSUs[NCH_ * 128 + t] = 0.f;
    for (int cc = NCH_ - 1; cc >= 0; --cc) {
      s += totU[(size_t)(b * NCH_ + cc) * 128 + t];
      CSUs[cc * 128 + t] = s;
    }
  } else {
    const int c2 = t - 128;
    float s2 = 0.f;
    for (int cc = 0; cc < NCH_; ++cc) {
      CPVs[cc * 128 + c2] = s2;
      s2 += totV[(size_t)(b * NCH_ + cc) * 128 + c2];
    }
    CPVs[NCH_ * 128 + c2] = s2;
  }
  __syncthreads();
  if (t < 64) {  // per-row scalars (lo/keep from rank kernel; no bsearch)
    float pv = p[b * N_ + i0 + t];
    int lk = lok[(size_t)b * N_ + i0 + t];
    keep_s[t] = (lk >> 16) & 1;
    int lo = lk & 0xFFFF;
    lo_s[t] = lo;
    float A = __expf(pv), Bv = __expf(0.01f * pv);
    A_s[t] = A; B_s[t] = Bv;
    float sus = SUS[(size_t)b * NP1_ + lo];
    float pvs = PVS[(size_t)b * NP1_ + lo];
    invD[t] = 1.0f / fmaf(A, sus, Bv * pvs);
  }
  __syncthreads();
  const int half = t >> 7, c = t & 127;
#pragma unroll 4
  for (int ii2 = 0; ii2 < 64; ii2 += 2) {
    int ii = ii2 + half;
    float outv;
    if (keep_s[ii]) {
      int lo = lo_s[ii];
      float A = A_s[ii], Bv = B_s[ii];
      float suc, pvc;
      if (lo < N_) {
        int chn = lo >> 6;   // / CL_
        size_t ro = ((size_t)(b * N_ + lo)) * 128;
        suc = SUl[ro + c] + CSUs[(chn + 1) * 128 + c];
        pvc = PVl[ro + c] + CPVs[chn * 128 + c];
      } else {
        suc = 0.f;
        pvc = CPVs[NCH_ * 128 + c];
      }
      outv = fmaxf(fmaf(A, suc, Bv * pvc) * invD[ii], 0.f);
    } else {
      outv = mr[c];
    }
    res[ii * 129 + c] = outv;
  }
  __syncthreads();
  // out[b][c][i] = res[i - i0][c]
#pragma unroll
  for (int pass = 0; pass < 8; ++pass) {
    int cc = (t >> 4) + pass * 16;
    int ii4 = (t & 15) * 4;
    float4 v;
    v.x = res[(ii4 + 0) * 129 + cc];
    v.y = res[(ii4 + 1) * 129 + cc];
    v.z = res[(ii4 + 2) * 129 + cc];
    v.w = res[(ii4 + 3) * 129 + cc];
    *(float4*)(out + ((size_t)(b * C_ + cc)) * N_ + i0 + ii4) = v;
  }
}

extern "C" void kernel_launch(void* const* d_in, const int* in_sizes, int n_in,
                              void* d_out, int out_size, void* d_ws, size_t ws_size,
                              hipStream_t stream) {
  (void)in_sizes; (void)n_in; (void)out_size; (void)ws_size;
  const float* x = (const float*)d_in[0];
  const float* W = (const float*)d_in[1];
  const float* a = (const float*)d_in[2];
  // d_in[3] (GL) is provably unused: adj > 0 everywhere.
  float* out = (float*)d_out;
  float* ws = (float*)d_ws;

  float* h    = ws + H_OFF;
  float* p    = ws + P_OFF;
  float* q    = ws + Q_OFF;
  int*   lok  = (int*)(ws + LOK_OFF);
  float* u_s  = ws + US_OFF;
  float* v_s  = ws + VS_OFF;
  int*   srt  = (int*)(ws + SRT_OFF);
  float* SUS  = ws + SUS_OFF;
  float* PVS  = ws + PVS_OFF;
  float* SUl  = ws + SUL_OFF;
  float* PVl  = ws + PVL_OFF;
  float* totU = ws + TOTU_OFF;
  float* totV = ws + TOTV_OFF;
  float* mpart = ws + MPART_OFF;

  k_pq<<<dim3((B_ * N_) / 64), dim3(256), 0, stream>>>(x, W, a, p, q);
  k_fuse<<<dim3(RANKB_ + (B_ * N_) / 64), dim3(512), 0, stream>>>(
      x, W, h, mpart, q, p, u_s, v_s, srt, lok);
  k_scan<<<dim3(256 + B_), dim3(256), 0, stream>>>(h, u_s, v_s, srt, SUl, PVl, totU, totV, SUS, PVS);
  k_out<<<dim3(B_ * 32), dim3(256), 0, stream>>>(p, lok, SUS, PVS, SUl, PVl, totU, totV, mpart, out);
}